// Round 1
// baseline (1288.201 us; speedup 1.0000x reference)
//
#include <hip/hip_runtime.h>
#include <hip/hip_bf16.h>

typedef __attribute__((ext_vector_type(8))) short short8;
typedef __attribute__((ext_vector_type(8))) __bf16 bf16x8;
typedef __attribute__((ext_vector_type(4))) float f32x4;
typedef __attribute__((ext_vector_type(2))) unsigned int u32x2;
typedef unsigned short u16;

// ---------------- helpers ----------------
__device__ __forceinline__ u16 f2b(float f) {          // fp32 -> bf16 RNE
  unsigned u = __builtin_bit_cast(unsigned, f);
  u = (u + 0x7fffu + ((u >> 16) & 1u)) >> 16;
  return (u16)u;
}
__device__ __forceinline__ bf16x8 ldb8(const u16* p) {  // 16B bf16x8 load
  return __builtin_bit_cast(bf16x8, *reinterpret_cast<const short8*>(p));
}
__device__ __forceinline__ void stage16(const void* g, void* l) {
  __builtin_amdgcn_global_load_lds((const __attribute__((address_space(1))) void*)g,
                                   (__attribute__((address_space(3))) void*)l,
                                   16, 0, 0);
}

// ---------------- embedding + sinusoidal positional encoding ----------------
__global__ __launch_bounds__(256)
void embed_kernel(const int* __restrict__ dec, const float* __restrict__ emb,
                  float* __restrict__ xf, u16* __restrict__ xb)
{
  int row = blockIdx.x;            // b*512 + pos
  int pos = row & 511;
  int tid = threadIdx.x;
  int tok = dec[row];
  const float* e = emb + (size_t)tok * 1024;
  int d0 = tid * 4;
  f32x4 y;
#pragma unroll
  for (int j = 0; j < 4; ++j) {
    int d = d0 + j;
    float fr = __expf((float)(d & ~1) * (-9.210340371976184f / 1024.f));
    float ang = (float)pos * fr;
    float pe = (d & 1) ? cosf(ang) : sinf(ang);
    y[j] = e[d] + pe;
  }
  *(f32x4*)(xf + (size_t)row * 1024 + d0) = y;
  u32x2 p;
  p[0] = ((unsigned)f2b(y[1]) << 16) | f2b(y[0]);
  p[1] = ((unsigned)f2b(y[3]) << 16) | f2b(y[2]);
  *(u32x2*)(xb + (size_t)row * 1024 + d0) = p;
}

// ---------------- pad masks (1.0 = blocked) ----------------
__global__ void mask_kernel(const int* __restrict__ dec, const int* __restrict__ enc,
                            float* __restrict__ mS, float* __restrict__ mC)
{
  int i = blockIdx.x * 256 + threadIdx.x;   // 0..2047
  if (i < 1024) mS[i] = (dec[i] == 0) ? 1.f : 0.f;
  else          mC[i - 1024] = (enc[i - 1024] == 0) ? 1.f : 0.f;
}

// ---------------- fp32 -> bf16 elementwise convert ----------------
__global__ void cvt_kernel(const float* __restrict__ s, u16* __restrict__ d)
{
  int i = blockIdx.x * 256 + threadIdx.x;
  f32x4 v = ((const f32x4*)s)[i];
  u32x2 p;
  p[0] = ((unsigned)f2b(v[1]) << 16) | f2b(v[0]);
  p[1] = ((unsigned)f2b(v[3]) << 16) | f2b(v[2]);
  ((u32x2*)d)[i] = p;
}

// ---------------- weight fp32 [K][N] -> bf16 [N][K] transpose-convert ----------------
__global__ __launch_bounds__(256)
void wconv_kernel(const float* __restrict__ src, u16* __restrict__ dst,
                  int K, int N, size_t sls, size_t dls)
{
  __shared__ u16 t[32 * 33];
  src += (size_t)blockIdx.z * sls;
  dst += (size_t)blockIdx.z * dls;
  int n0 = blockIdx.x * 32, k0 = blockIdx.y * 32;
  int c = threadIdx.x & 31, r8 = threadIdx.x >> 5;
#pragma unroll
  for (int j = 0; j < 4; ++j) {
    int r = r8 + j * 8;
    t[c * 33 + r] = f2b(src[(size_t)(k0 + r) * N + n0 + c]);
  }
  __syncthreads();
#pragma unroll
  for (int j = 0; j < 4; ++j) {
    int n = r8 + j * 8;
    dst[(size_t)(n0 + n) * K + k0 + c] = t[n * 33 + c];
  }
}

// ---------------- GEMM: C[M,N] = A[M,K](bf16) @ Bt[N,K]^T(bf16) ----------------
// EPI: 0 = bf16 out, 1 = relu -> bf16 out, 2 = f32 out
template<int EPI>
__global__ __launch_bounds__(256)
void gemm_bt(const u16* __restrict__ A, const u16* __restrict__ Bt,
             void* __restrict__ Cout, int M, int N, int K)
{
  __shared__ u16 As[128 * 32];   // [m][k]
  __shared__ u16 Bs[128 * 32];   // [n][k]
  int tid  = threadIdx.x;
  int lane = tid & 63;
  int w    = tid >> 6;
  int grp  = lane >> 4, li = lane & 15;
  int wm = w >> 1, wn = w & 1;                 // 2x2 wave grid, 64x64 each
  int m0 = blockIdx.y * 128, n0 = blockIdx.x * 128;
  f32x4 acc[4][4] = {};
  int c0 = tid, c1 = tid + 256;                // 16B chunk ids (512 per 8KB tile)
  int r0 = c0 >> 2, k0b = (c0 & 3) * 8;
  int r1 = c1 >> 2, k1b = (c1 & 3) * 8;
  for (int k0 = 0; k0 < K; k0 += 32) {
    __syncthreads();
    stage16(A  + (size_t)(m0 + r0) * K + k0 + k0b, (u16*)As + c0 * 8);
    stage16(A  + (size_t)(m0 + r1) * K + k0 + k1b, (u16*)As + c1 * 8);
    stage16(Bt + (size_t)(n0 + r0) * K + k0 + k0b, (u16*)Bs + c0 * 8);
    stage16(Bt + (size_t)(n0 + r1) * K + k0 + k1b, (u16*)Bs + c1 * 8);
    __syncthreads();
    bf16x8 af[4], bf[4];
#pragma unroll
    for (int i = 0; i < 4; ++i) {
      af[i] = ldb8(&As[(wm * 64 + i * 16 + li) * 32 + grp * 8]);
      bf[i] = ldb8(&Bs[(wn * 64 + i * 16 + li) * 32 + grp * 8]);
    }
#pragma unroll
    for (int i = 0; i < 4; ++i)
#pragma unroll
      for (int j = 0; j < 4; ++j)
        acc[i][j] = __builtin_amdgcn_mfma_f32_16x16x32_bf16(af[i], bf[j], acc[i][j], 0, 0, 0);
  }
  // C/D layout: col = lane&15, row = (lane>>4)*4 + r
#pragma unroll
  for (int i = 0; i < 4; ++i)
#pragma unroll
    for (int j = 0; j < 4; ++j) {
      int mrow = m0 + wm * 64 + i * 16 + grp * 4;
      int ncol = n0 + wn * 64 + j * 16 + li;
#pragma unroll
      for (int r = 0; r < 4; ++r) {
        float v = acc[i][j][r];
        if (EPI == 1) v = fmaxf(v, 0.f);
        if (EPI == 2) ((float*)Cout)[(size_t)(mrow + r) * N + ncol] = v;
        else          ((u16*)Cout)[(size_t)(mrow + r) * N + ncol] = f2b(v);
      }
    }
}

// ---------------- flash attention ----------------
// Block = (q-tile of 64 rows, one (b,h)); 4 waves x 16 q-rows each.
// Q/K read from global (L2-resident); V staged transposed in LDS; P via per-wave LDS.
template<int CAUSAL>
__global__ __launch_bounds__(256)
void flash_kernel(const u16* __restrict__ Qp, int qstride,
                  const u16* __restrict__ Kp, const u16* __restrict__ Vp, int kvstride,
                  const float* __restrict__ mask, u16* __restrict__ Out)
{
  __shared__ u16 VT[64 * 72];       // [d][k], pad 72 to kill bank conflicts
  __shared__ u16 P[4][16 * 72];     // per-wave [q][k]
  int qt = blockIdx.x;              // 0..7
  int bh = blockIdx.y;              // 0..31
  int b = bh >> 4, h = bh & 15;
  int tid = threadIdx.x, w = tid >> 6, lane = tid & 63;
  int grp = lane >> 4, li = lane & 15;
  int bL = b * 512;

  const u16* qbase = Qp + (size_t)(bL + qt * 64 + w * 16 + li) * qstride + h * 64 + grp * 8;
  bf16x8 qf0 = ldb8(qbase);
  bf16x8 qf1 = ldb8(qbase + 32);

  f32x4 ctxa[4] = {};
  float mrun[4], lrun[4];
#pragma unroll
  for (int r = 0; r < 4; ++r) { mrun[r] = -3e38f; lrun[r] = 0.f; }

  int ktiles = CAUSAL ? (qt + 1) : 8;
  int vk = tid >> 2, vdc = tid & 3;          // V staging role: row vk, 16-d chunk vdc
  const float* maskb = mask + bL;

  for (int kt = 0; kt < ktiles; ++kt) {
    int kb = kt * 64;
    __syncthreads();                         // prior PV reads of VT done
    {
      const u16* vsrc = Vp + (size_t)(bL + kb + vk) * kvstride + h * 64 + vdc * 16;
      short8 v0 = *(const short8*)vsrc;
      short8 v1 = *(const short8*)(vsrc + 8);
#pragma unroll
      for (int j = 0; j < 8; ++j) VT[(vdc * 16 + j) * 72 + vk] = (u16)v0[j];
#pragma unroll
      for (int j = 0; j < 8; ++j) VT[(vdc * 16 + 8 + j) * 72 + vk] = (u16)v1[j];
    }
    __syncthreads();

    // S = Q K^T  (A=Q frag, B=K rows d-contig)
    f32x4 s[4];
#pragma unroll
    for (int k4 = 0; k4 < 4; ++k4) {
      const u16* kbp = Kp + (size_t)(bL + kb + k4 * 16 + li) * kvstride + h * 64 + grp * 8;
      bf16x8 kf0 = ldb8(kbp);
      bf16x8 kf1 = ldb8(kbp + 32);
      f32x4 z = {};
      z = __builtin_amdgcn_mfma_f32_16x16x32_bf16(qf0, kf0, z, 0, 0, 0);
      z = __builtin_amdgcn_mfma_f32_16x16x32_bf16(qf1, kf1, z, 0, 0, 0);
      s[k4] = z;
    }
    // scale + mask (exactly: blocked -> -1e9, else s/8)
#pragma unroll
    for (int k4 = 0; k4 < 4; ++k4) {
      int kg = kb + k4 * 16 + li;
      float pm = maskb[kg];
#pragma unroll
      for (int r = 0; r < 4; ++r) {
        int qg = qt * 64 + w * 16 + grp * 4 + r;
        bool blocked = (pm > 0.5f) || (CAUSAL && kg > qg);
        s[k4][r] = blocked ? -1e9f : s[k4][r] * 0.125f;
      }
    }
    // online softmax per q-row (rows live in 16-lane groups)
#pragma unroll
    for (int r = 0; r < 4; ++r) {
      float tm = fmaxf(fmaxf(s[0][r], s[1][r]), fmaxf(s[2][r], s[3][r]));
      tm = fmaxf(tm, __shfl_xor(tm, 1));
      tm = fmaxf(tm, __shfl_xor(tm, 2));
      tm = fmaxf(tm, __shfl_xor(tm, 4));
      tm = fmaxf(tm, __shfl_xor(tm, 8));
      float mn = fmaxf(mrun[r], tm);
      float corr = __expf(mrun[r] - mn);
      mrun[r] = mn;
      float psum = 0.f;
#pragma unroll
      for (int k4 = 0; k4 < 4; ++k4) {
        float p = __expf(s[k4][r] - mn);
        s[k4][r] = p;
        psum += p;
      }
      psum += __shfl_xor(psum, 1);
      psum += __shfl_xor(psum, 2);
      psum += __shfl_xor(psum, 4);
      psum += __shfl_xor(psum, 8);
      lrun[r] = lrun[r] * corr + psum;
#pragma unroll
      for (int dt = 0; dt < 4; ++dt) ctxa[dt][r] *= corr;
    }
    // P -> LDS (bf16)
    u16* Pw = P[w];
#pragma unroll
    for (int k4 = 0; k4 < 4; ++k4)
#pragma unroll
      for (int r = 0; r < 4; ++r)
        Pw[(grp * 4 + r) * 72 + k4 * 16 + li] = f2b(s[k4][r]);
    // PV: A = P (q-row = lane&15, k contiguous), B = V^T rows (d = lane&15, k contig)
    bf16x8 pa0 = ldb8(&Pw[li * 72 + grp * 8]);
    bf16x8 pa1 = ldb8(&Pw[li * 72 + 32 + grp * 8]);
#pragma unroll
    for (int dt = 0; dt < 4; ++dt) {
      const u16* vtb = &VT[(dt * 16 + li) * 72 + grp * 8];
      bf16x8 vb0 = ldb8(vtb);
      bf16x8 vb1 = ldb8(vtb + 32);
      ctxa[dt] = __builtin_amdgcn_mfma_f32_16x16x32_bf16(pa0, vb0, ctxa[dt], 0, 0, 0);
      ctxa[dt] = __builtin_amdgcn_mfma_f32_16x16x32_bf16(pa1, vb1, ctxa[dt], 0, 0, 0);
    }
  }
  // write ctx / l  -> Out[b*512+q][h*64+d] bf16
#pragma unroll
  for (int dt = 0; dt < 4; ++dt)
#pragma unroll
    for (int r = 0; r < 4; ++r) {
      float v = ctxa[dt][r] / lrun[r];
      int qg = qt * 64 + w * 16 + grp * 4 + r;
      Out[(size_t)(bL + qg) * 1024 + h * 64 + dt * 16 + li] = f2b(v);
    }
}

// ---------------- residual add + LayerNorm (row per block) ----------------
__global__ __launch_bounds__(256)
void add_ln_kernel(const float* t, const float* res, float* xf, u16* xb)
{
  int row = blockIdx.x, tid = threadIdx.x;
  f32x4 v  = ((const f32x4*)(t   + (size_t)row * 1024))[tid];
  f32x4 rv = ((const f32x4*)(res + (size_t)row * 1024))[tid];
  v = v + rv;
  float s = v[0] + v[1] + v[2] + v[3];
  float q = v[0] * v[0] + v[1] * v[1] + v[2] * v[2] + v[3] * v[3];
#pragma unroll
  for (int m = 1; m <= 32; m <<= 1) { s += __shfl_xor(s, m); q += __shfl_xor(q, m); }
  __shared__ float ps[4], pq[4];
  int w = tid >> 6;
  if ((tid & 63) == 0) { ps[w] = s; pq[w] = q; }
  __syncthreads();
  s = ps[0] + ps[1] + ps[2] + ps[3];
  q = pq[0] + pq[1] + pq[2] + pq[3];
  float mu  = s * 0.0009765625f;
  float var = q * 0.0009765625f - mu * mu;
  float rs  = rsqrtf(var + 1e-5f);
  f32x4 y;
#pragma unroll
  for (int j = 0; j < 4; ++j) y[j] = (v[j] - mu) * rs;
  ((f32x4*)(xf + (size_t)row * 1024))[tid] = y;
  u32x2 p;
  p[0] = ((unsigned)f2b(y[1]) << 16) | f2b(y[0]);
  p[1] = ((unsigned)f2b(y[3]) << 16) | f2b(y[2]);
  ((u32x2*)(xb + (size_t)row * 1024))[tid] = p;
}

// ---------------- orchestration ----------------
extern "C" void kernel_launch(void* const* d_in, const int* in_sizes, int n_in,
                              void* d_out, int out_size, void* d_ws, size_t ws_size,
                              hipStream_t stream)
{
  const int*   dec    = (const int*)d_in[0];
  const int*   encin  = (const int*)d_in[1];
  const float* encout = (const float*)d_in[2];
  const float* emb    = (const float*)d_in[3];
  const float* sWq = (const float*)d_in[4];
  const float* sWk = (const float*)d_in[5];
  const float* sWv = (const float*)d_in[6];
  const float* sWo = (const float*)d_in[7];
  const float* cWq = (const float*)d_in[8];
  const float* cWk = (const float*)d_in[9];
  const float* cWv = (const float*)d_in[10];
  const float* cWo = (const float*)d_in[11];
  const float* fW1 = (const float*)d_in[12];
  const float* fW2 = (const float*)d_in[13];

  char* wsp = (char*)d_ws;
  size_t off = 0;
  auto alloc = [&](size_t bytes) -> void* {
    void* p = wsp + off;
    off += (bytes + 255) & ~(size_t)255;
    return p;
  };

  float* x    = (float*)alloc((size_t)1024 * 1024 * 4);
  float* tmp  = (float*)alloc((size_t)1024 * 1024 * 4);
  u16* xb     = (u16*)alloc((size_t)1024 * 1024 * 2);
  u16* qkv    = (u16*)alloc((size_t)1024 * 3072 * 2);
  u16* ctxb   = (u16*)alloc((size_t)1024 * 1024 * 2);
  u16* q2     = (u16*)alloc((size_t)1024 * 1024 * 2);
  u16* hbuf   = (u16*)alloc((size_t)1024 * 4096 * 2);
  u16* encb   = (u16*)alloc((size_t)1024 * 1024 * 2);
  float* maskS = (float*)alloc(1024 * 4);
  float* maskC = (float*)alloc(1024 * 4);

  const size_t W_SQ  = (size_t)1024 * 1024;
  const size_t W_QKV = (size_t)3072 * 1024;
  const size_t W_KV  = (size_t)2048 * 1024;
  const size_t W_FF  = (size_t)4096 * 1024;

  size_t full_bytes = 2 * 4 * (W_QKV + W_KV + 3 * W_SQ + 2 * W_FF) + (size_t)1024 * 8192 * 2;
  bool full = (ws_size >= off + full_bytes + 8192);
  size_t nl = full ? 4 : 1;

  u16* Wqkv_t = (u16*)alloc(nl * W_QKV * 2);
  u16* cKV_t  = (u16*)alloc(nl * W_KV * 2);
  u16* cWq_t  = (u16*)alloc(nl * W_SQ * 2);
  u16* sWo_t  = (u16*)alloc(nl * W_SQ * 2);
  u16* cWo_t  = (u16*)alloc(nl * W_SQ * 2);
  u16* W1_t   = (u16*)alloc(nl * W_FF * 2);
  u16* W2_t   = (u16*)alloc(nl * W_FF * 2);
  u16* encKV  = (u16*)alloc((size_t)1024 * (full ? 8192 : 2048) * 2);

  // ---- prep ----
  embed_kernel<<<dim3(1024), 256, 0, stream>>>(dec, emb, x, xb);
  mask_kernel<<<dim3(8), 256, 0, stream>>>(dec, encin, maskS, maskC);
  cvt_kernel<<<dim3(1024), 256, 0, stream>>>(encout, encb);

  if (full) {
    wconv_kernel<<<dim3(32, 32, 4), 256, 0, stream>>>(sWq, Wqkv_t,            1024, 1024, W_SQ, W_QKV);
    wconv_kernel<<<dim3(32, 32, 4), 256, 0, stream>>>(sWk, Wqkv_t + W_SQ,     1024, 1024, W_SQ, W_QKV);
    wconv_kernel<<<dim3(32, 32, 4), 256, 0, stream>>>(sWv, Wqkv_t + 2 * W_SQ, 1024, 1024, W_SQ, W_QKV);
    wconv_kernel<<<dim3(32, 32, 4), 256, 0, stream>>>(sWo, sWo_t, 1024, 1024, W_SQ, W_SQ);
    wconv_kernel<<<dim3(32, 32, 4), 256, 0, stream>>>(cWq, cWq_t, 1024, 1024, W_SQ, W_SQ);
    wconv_kernel<<<dim3(32, 32, 4), 256, 0, stream>>>(cWk, cKV_t,        1024, 1024, W_SQ, W_KV);
    wconv_kernel<<<dim3(32, 32, 4), 256, 0, stream>>>(cWv, cKV_t + W_SQ, 1024, 1024, W_SQ, W_KV);
    wconv_kernel<<<dim3(32, 32, 4), 256, 0, stream>>>(cWo, cWo_t, 1024, 1024, W_SQ, W_SQ);
    wconv_kernel<<<dim3(128, 32, 4), 256, 0, stream>>>(fW1, W1_t, 1024, 4096, W_FF, W_FF);
    wconv_kernel<<<dim3(32, 128, 4), 256, 0, stream>>>(fW2, W2_t, 4096, 1024, W_FF, W_FF);
    gemm_bt<0><<<dim3(64, 8), 256, 0, stream>>>(encb, cKV_t, encKV, 1024, 8192, 1024);
  }

  for (int l = 0; l < 4; ++l) {
    if (!full) {
      wconv_kernel<<<dim3(32, 32, 1), 256, 0, stream>>>(sWq + l * W_SQ, Wqkv_t,            1024, 1024, 0, 0);
      wconv_kernel<<<dim3(32, 32, 1), 256, 0, stream>>>(sWk + l * W_SQ, Wqkv_t + W_SQ,     1024, 1024, 0, 0);
      wconv_kernel<<<dim3(32, 32, 1), 256, 0, stream>>>(sWv + l * W_SQ, Wqkv_t + 2 * W_SQ, 1024, 1024, 0, 0);
      wconv_kernel<<<dim3(32, 32, 1), 256, 0, stream>>>(sWo + l * W_SQ, sWo_t, 1024, 1024, 0, 0);
      wconv_kernel<<<dim3(32, 32, 1), 256, 0, stream>>>(cWq + l * W_SQ, cWq_t, 1024, 1024, 0, 0);
      wconv_kernel<<<dim3(32, 32, 1), 256, 0, stream>>>(cWk + l * W_SQ, cKV_t,        1024, 1024, 0, 0);
      wconv_kernel<<<dim3(32, 32, 1), 256, 0, stream>>>(cWv + l * W_SQ, cKV_t + W_SQ, 1024, 1024, 0, 0);
      wconv_kernel<<<dim3(32, 32, 1), 256, 0, stream>>>(cWo + l * W_SQ, cWo_t, 1024, 1024, 0, 0);
      wconv_kernel<<<dim3(128, 32, 1), 256, 0, stream>>>(fW1 + l * W_FF, W1_t, 1024, 4096, 0, 0);
      wconv_kernel<<<dim3(32, 128, 1), 256, 0, stream>>>(fW2 + l * W_FF, W2_t, 4096, 1024, 0, 0);
      gemm_bt<0><<<dim3(16, 8), 256, 0, stream>>>(encb, cKV_t, encKV, 1024, 2048, 1024);
    }
    u16* wqkv = Wqkv_t + (full ? (size_t)l * W_QKV : 0);
    u16* wso  = sWo_t  + (full ? (size_t)l * W_SQ : 0);
    u16* wcq  = cWq_t  + (full ? (size_t)l * W_SQ : 0);
    u16* wco  = cWo_t  + (full ? (size_t)l * W_SQ : 0);
    u16* w1   = W1_t   + (full ? (size_t)l * W_FF : 0);
    u16* w2   = W2_t   + (full ? (size_t)l * W_FF : 0);
    const u16* kvp = encKV + (full ? (size_t)l * 2048 : 0);
    int kvstr = full ? 8192 : 2048;

    // self-attention
    gemm_bt<0><<<dim3(24, 8), 256, 0, stream>>>(xb, wqkv, qkv, 1024, 3072, 1024);
    flash_kernel<1><<<dim3(8, 32), 256, 0, stream>>>(qkv, 3072, qkv + 1024, qkv + 2048, 3072, maskS, ctxb);
    gemm_bt<2><<<dim3(8, 8), 256, 0, stream>>>(ctxb, wso, tmp, 1024, 1024, 1024);
    add_ln_kernel<<<dim3(1024), 256, 0, stream>>>(tmp, x, x, xb);

    // cross-attention
    gemm_bt<0><<<dim3(8, 8), 256, 0, stream>>>(xb, wcq, q2, 1024, 1024, 1024);
    flash_kernel<0><<<dim3(8, 32), 256, 0, stream>>>(q2, 1024, kvp, kvp + 1024, kvstr, maskC, ctxb);
    gemm_bt<2><<<dim3(8, 8), 256, 0, stream>>>(ctxb, wco, tmp, 1024, 1024, 1024);
    add_ln_kernel<<<dim3(1024), 256, 0, stream>>>(tmp, x, x, xb);

    // FFN
    gemm_bt<1><<<dim3(32, 8), 256, 0, stream>>>(xb, w1, hbuf, 1024, 4096, 1024);
    gemm_bt<2><<<dim3(8, 8), 256, 0, stream>>>(hbuf, w2, tmp, 1024, 1024, 4096);
    float* xo = (l == 3) ? (float*)d_out : x;
    add_ln_kernel<<<dim3(1024), 256, 0, stream>>>(tmp, x, xo, xb);
  }
}